// Round 6
// baseline (402.407 us; speedup 1.0000x reference)
//
#include <hip/hip_runtime.h>
#include <math.h>

#define B_ 16
#define H_ 16
#define M_ 256
#define N_ 576
#define D_ 1024
#define BK 64
#define LDS_STRIDE (BK + 8)
#define NROWS (B_ * N_ + B_ * M_)   // 13312 feature rows to normalize

constexpr float EPS_ = 1e-8f;
constexpr float FI_ = 0.90909090909090906f;   // RHO/(RHO+EPSILON) = 1/1.1

typedef __bf16 bf16x8 __attribute__((ext_vector_type(8)));
typedef float f32x4 __attribute__((ext_vector_type(4)));

__device__ __forceinline__ float wave_reduce(float v) {
#pragma unroll
  for (int o = 32; o > 0; o >>= 1) v += __shfl_down(v, o, 64);
  return v;
}

__device__ __forceinline__ unsigned short f2bf(float f) {
  union { float f; unsigned u; } a; a.f = f;
  unsigned r = a.u + 0x7fff + ((a.u >> 16) & 1);   // RNE
  return (unsigned short)(r >> 16);
}

__device__ __forceinline__ float bits2f(unsigned u) {
  union { unsigned u; float f; } a; a.u = u;
  return a.f;
}

// SL[b,m,n] = sum_h log(student[b,h,m,n]+EPS). Dense: 256 threads all active.
// grid (M*N/4/256 = 144, B). Contiguous 4 KB per block per h-plane.
__global__ __launch_bounds__(256) void sumlog_kernel(const float* __restrict__ student,
                                                     float* __restrict__ SL) {
  const int b = blockIdx.y;
  const size_t mn4 = (size_t)blockIdx.x * 256 + threadIdx.x;  // < 36864
  const float* st = student + (size_t)b * H_ * M_ * N_ + mn4 * 4;
  float4 acc = {0.f, 0.f, 0.f, 0.f};
#pragma unroll
  for (int h = 0; h < H_; ++h) {
    float4 s4 = *(const float4*)&st[(size_t)h * M_ * N_];
    acc.x += __logf(s4.x + EPS_);
    acc.y += __logf(s4.y + EPS_);
    acc.z += __logf(s4.z + EPS_);
    acc.w += __logf(s4.w + EPS_);
  }
  *(float4*)&SL[(size_t)b * M_ * N_ + mn4 * 4] = acc;
}

// L2-normalize + bf16-cast vis (B*N rows) and txt (B*M rows), one wave per row.
__global__ __launch_bounds__(256) void prep_kernel(const float* __restrict__ vis,
                                                   const float* __restrict__ txt,
                                                   unsigned short* __restrict__ xb,
                                                   unsigned short* __restrict__ yb) {
  const int lane = threadIdx.x & 63;
  int wave = blockIdx.x * 4 + (threadIdx.x >> 6);
  const float* src;
  unsigned short* dst;
  if (wave < B_ * N_) {
    src = vis + (size_t)wave * D_;
    dst = xb + (size_t)wave * D_;
  } else {
    int r = wave - B_ * N_;
    src = txt + (size_t)r * D_;
    dst = yb + (size_t)r * D_;
  }
  float4 v[4];
  float s = 0.f;
#pragma unroll
  for (int it = 0; it < 4; ++it) {
    v[it] = *(const float4*)&src[it * 256 + lane * 4];
    s += v[it].x * v[it].x + v[it].y * v[it].y + v[it].z * v[it].z + v[it].w * v[it].w;
  }
  s = wave_reduce(s);
  s = __shfl(s, 0, 64);
  float inv = rsqrtf(s + 1e-12f);
#pragma unroll
  for (int it = 0; it < 4; ++it) {
    ushort4 pk;
    pk.x = f2bf(v[it].x * inv);
    pk.y = f2bf(v[it].y * inv);
    pk.z = f2bf(v[it].z * inv);
    pk.w = f2bf(v[it].w * inv);
    *(ushort4*)&dst[it * 256 + lane * 4] = pk;
  }
}

// K[b,m,n] = bf16(exp(10*(dot(yb[b,m],xb[b,n]) - 1))), bf16 MFMA 16x16x32.
__global__ __launch_bounds__(256) void gemm_k_mfma(const unsigned short* __restrict__ xb,
                                                   const unsigned short* __restrict__ yb,
                                                   unsigned short* __restrict__ Kw) {
  __shared__ unsigned short As[64][LDS_STRIDE];  // y rows (m)
  __shared__ unsigned short Bs[64][LDS_STRIDE];  // x rows (n)
  const int b = blockIdx.z;
  const int m0 = blockIdx.y * 64;
  const int n0 = blockIdx.x * 64;
  const unsigned short* Y = yb + (size_t)b * M_ * D_;
  const unsigned short* X = xb + (size_t)b * N_ * D_;
  const int t = threadIdx.x;
  const int lane = t & 63;
  const int w = t >> 6;
  const int wm = (w & 1) * 32;
  const int wn = (w >> 1) * 32;
  const int lr = t >> 3;           // 0..31 staging row
  const int lc = (t & 7) * 8;      // staging col (bf16 units, 16B chunks)
  const int fr = lane & 15;        // fragment row within 16
  const int fk = (lane >> 4) * 8;  // fragment k offset

  f32x4 acc[2][2] = {};
  for (int k0 = 0; k0 < D_; k0 += BK) {
#pragma unroll
    for (int p = 0; p < 2; ++p) {
      *(uint4*)&As[lr + 32 * p][lc] = *(const uint4*)&Y[(size_t)(m0 + lr + 32 * p) * D_ + k0 + lc];
      *(uint4*)&Bs[lr + 32 * p][lc] = *(const uint4*)&X[(size_t)(n0 + lr + 32 * p) * D_ + k0 + lc];
    }
    __syncthreads();
#pragma unroll
    for (int ks = 0; ks < BK; ks += 32) {
      bf16x8 a[2], bfr[2];
#pragma unroll
      for (int i = 0; i < 2; ++i) {
        a[i] = *(const bf16x8*)&As[wm + i * 16 + fr][ks + fk];
        bfr[i] = *(const bf16x8*)&Bs[wn + i * 16 + fr][ks + fk];
      }
#pragma unroll
      for (int i = 0; i < 2; ++i)
#pragma unroll
        for (int j = 0; j < 2; ++j)
          acc[i][j] = __builtin_amdgcn_mfma_f32_16x16x32_bf16(a[i], bfr[j], acc[i][j], 0, 0, 0);
    }
    __syncthreads();
  }

  // C/D layout: m = (lane>>4)*4 + reg, n = lane&15
  const int cm = (lane >> 4) * 4;
  const int cn = lane & 15;
#pragma unroll
  for (int i = 0; i < 2; ++i)
#pragma unroll
    for (int j = 0; j < 2; ++j)
#pragma unroll
      for (int rg = 0; rg < 4; ++rg) {
        int m = m0 + wm + i * 16 + cm + rg;
        int n = n0 + wn + j * 16 + cn;
        Kw[((size_t)b * M_ + m) * N_ + n] = f2bf(expf(10.f * (acc[i][j][rg] - 1.f)));
      }
}

// Fully-fused Sinkhorn + loss epilogue. One block per batch, 1024 threads.
// Wave w owns K rows 16w..16w+15; lane owns columns n = lane + 64j (j<9).
// K held register-resident as 72 packed uints (rows 2p / 2p+1 in lo/hi).
// After 5 u/v iterations: partial[b,m] = -mask*s2/(s1+EPS); 16 atomics total.
__global__ __launch_bounds__(1024) void sinkloss_kernel(const unsigned short* __restrict__ Kw,
                                                        const float* __restrict__ SL,
                                                        const float* __restrict__ mask,
                                                        float* __restrict__ out) {
  __shared__ float partv[16][N_];   // 36 KB
  __shared__ float sv[N_];
  __shared__ float su[M_];
  __shared__ float snu[M_];
  __shared__ float smask[M_];
  __shared__ float srow[M_];
  __shared__ float sred[16];
  const int b = blockIdx.x;
  const int t = threadIdx.x;
  const int lane = t & 63;
  const int w = t >> 6;           // 0..15
  const int r0 = w * 16;
  const unsigned short* Kb = Kw + (size_t)b * M_ * N_;

  // masksum -> nu; v init
  float mv = (t < M_) ? mask[b * M_ + t] : 0.f;
  float wsum = wave_reduce(mv);
  if (t < M_ && lane == 0) sred[w] = wsum;
  if (t < N_) sv[t] = 1.f;
  if (t < M_) smask[t] = mv;
  __syncthreads();
  if (t < M_) {
    float msum = sred[0] + sred[1] + sred[2] + sred[3];
    snu[t] = mv / (msum + EPS_);
  }

  // Load K tile into registers: kreg[j][p] packs rows r0+2p (lo), r0+2p+1 (hi).
  unsigned kreg[9][8];
#pragma unroll
  for (int j = 0; j < 9; ++j)
#pragma unroll
    for (int p = 0; p < 8; ++p) {
      unsigned lo = Kb[(size_t)(r0 + 2 * p) * N_ + lane + 64 * j];
      unsigned hi = Kb[(size_t)(r0 + 2 * p + 1) * N_ + lane + 64 * j];
      kreg[j][p] = lo | (hi << 16);
    }
#define KVAL(j, i) bits2f(((i) & 1) ? (kreg[j][(i) >> 1] & 0xffff0000u) : (kreg[j][(i) >> 1] << 16))

  __syncthreads();

  for (int it = 0; it < 5; ++it) {
    // u-step: row sums K·v
#pragma unroll
    for (int i = 0; i < 16; ++i) {
      float s = 0.f;
#pragma unroll
      for (int j = 0; j < 9; ++j) s += KVAL(j, i) * sv[lane + 64 * j];
      s = wave_reduce(s);
      if (lane == 0) srow[r0 + i] = s;
    }
    __syncthreads();
    if (t < M_) su[t] = powf(snu[t] / (srow[t] + EPS_), FI_);
    __syncthreads();
    // v-step: col sums K^T·u
#pragma unroll
    for (int j = 0; j < 9; ++j) {
      float s = 0.f;
#pragma unroll
      for (int i = 0; i < 16; ++i) s += KVAL(j, i) * su[r0 + i];
      partv[w][lane + 64 * j] = s;
    }
    __syncthreads();
    if (t < N_) {
      float s = 0.f;
#pragma unroll
      for (int ww = 0; ww < 16; ++ww) s += partv[ww][t];
      sv[t] = powf((1.f / (float)N_) / (s + EPS_), FI_);
    }
    __syncthreads();
  }

  // Epilogue: per row r: s1 = sum K*v, s2 = sum K*v*SL; acc -= mask*s2/(s1+EPS)
  float acc = 0.f;
#pragma unroll
  for (int i = 0; i < 16; ++i) {
    const int r = r0 + i;
    const float* slp = SL + ((size_t)b * M_ + r) * N_;
    float s1 = 0.f, s2 = 0.f;
#pragma unroll
    for (int j = 0; j < 9; ++j) {
      float kv = KVAL(j, i) * sv[lane + 64 * j];
      s1 += kv;
      s2 += kv * slp[lane + 64 * j];
    }
    s1 = wave_reduce(s1);
    s2 = wave_reduce(s2);
    if (lane == 0) acc -= smask[r] * s2 / (s1 + EPS_);
  }
  if (lane == 0) sred[w] = acc;
  __syncthreads();
  if (t == 0) {
    float tot = 0.f;
#pragma unroll
    for (int ww = 0; ww < 16; ++ww) tot += sred[ww];
    atomicAdd(out, tot * (1.f / ((float)B_ * H_ * M_)));
  }
#undef KVAL
}

extern "C" void kernel_launch(void* const* d_in, const int* in_sizes, int n_in,
                              void* d_out, int out_size, void* d_ws, size_t ws_size,
                              hipStream_t stream) {
  const float* student = (const float*)d_in[0];  // (B,H,M,N)
  const float* vis = (const float*)d_in[1];      // (B,N,D)
  const float* txt = (const float*)d_in[2];      // (B,M,D)
  const float* mask = (const float*)d_in[3];     // (B,M)
  float* out = (float*)d_out;

  char* p = (char*)d_ws;
  unsigned short* Kb = (unsigned short*)p; p += (size_t)B_ * M_ * N_ * 2;   // 4.7 MB
  unsigned short* xb = (unsigned short*)p; p += (size_t)B_ * N_ * D_ * 2;   // 18.9 MB
  unsigned short* yb = (unsigned short*)p; p += (size_t)B_ * M_ * D_ * 2;   // 8.4 MB
  float* SL = (float*)p;      p += (size_t)B_ * M_ * N_ * 4;                // 9.4 MB

  hipMemsetAsync(d_out, 0, sizeof(float), stream);
  // 151 MB streaming head-reduction first (independent of everything).
  sumlog_kernel<<<dim3(M_ * N_ / 4 / 256, B_), 256, 0, stream>>>(student, SL);
  prep_kernel<<<NROWS / 4, 256, 0, stream>>>(vis, txt, xb, yb);
  gemm_k_mfma<<<dim3(N_ / 64, M_ / 64, B_), 256, 0, stream>>>(xb, yb, Kb);
  sinkloss_kernel<<<B_, 1024, 0, stream>>>(Kb, SL, mask, out);
}